// Round 1
// baseline (10678.921 us; speedup 1.0000x reference)
//
#include <hip/hip_runtime.h>
#include <hip/hip_bf16.h>
#include <cstdint>
#include <cstddef>

// LSTM w/ projection + peepholes, MI355X gfx950.
// T=512 N=32 D=H=P=1024 L=4.
// Reformulation: pass m = o*tanh(c) between layers/steps; fold whm into
//   W1^l = whm^{l-1} @ wih^l   (l>=1; layer0 uses wih directly)
//   W2^l = whm^l    @ whh^l
// Per layer-step: a = bias + [in; m_prev](32x2048) @ Wcat^T(4096x2048 bf16).
// Diagonal pipeline: slot s runs layer l at t = s - l  (515 slot kernels).
// Workspace layout (bytes), total 103,219,200 (~98.4 MB):
//   Wcat  : 4 * 4096*2048 bf16 = 67,108,864   (stored transposed: [n][k])
//   m3    : 512*32*1024  bf16 = 33,554,432    (layer-3 m for ys epilogue)
//   ring  : 3*2*32*1024  bf16 =    393,216    (layers 0-2 m ping-pong)
//   r0    : 4*32*4096    f32  =  2,097,152    (h0 @ whh, t=0 substitute)
//   bias  : 4*4096       f32  =     65,536

#define TT 512
#define NBATCH 32
#define HID 1024
#define G4 4096
#define KCAT 2048

typedef __attribute__((ext_vector_type(4))) float f32x4;
typedef __attribute__((ext_vector_type(8))) short bf16x8;

static __device__ __forceinline__ uint16_t f2bf(float f) {
  uint32_t u = __builtin_bit_cast(uint32_t, f);
  uint32_t lsb = (u >> 16) & 1u;
  u += 0x7fffu + lsb;                 // round-to-nearest-even
  return (uint16_t)(u >> 16);
}

static __device__ __forceinline__ f32x4 mfma16x16(bf16x8 a, bf16x8 b, f32x4 c) {
  return __builtin_amdgcn_mfma_f32_16x16x32_bf16(a, b, c, 0, 0, 0);
}

static __device__ __forceinline__ float sigm(float v) {
  return 1.f / (1.f + __expf(-v));
}
static __device__ __forceinline__ float tanh_(float v) {
  float a = fabsf(v);
  float e = __expf(-2.f * a);
  float t = (1.f - e) / (1.f + e);
  return v < 0.f ? -t : t;
}

// ---------------- small helpers ----------------
__global__ void __launch_bounds__(256) add_bias(const float* __restrict__ a,
                                                const float* __restrict__ b,
                                                float* __restrict__ o, int n) {
  int i = blockIdx.x * 256 + threadIdx.x;
  if (i < n) o[i] = a[i] + b[i];
}

// src f32 (K x N) row-major -> dst bf16 [n][k] (ld ldd), 64x64 tiles
__global__ void __launch_bounds__(256) transpose_cast(const float* __restrict__ src, int lds,
                                                      uint16_t* __restrict__ dst, int ldd) {
  const int k0 = blockIdx.x * 64;
  const int n0 = blockIdx.y * 64;
  __shared__ float tile[64][65];
  const int tid = threadIdx.x;
#pragma unroll
  for (int p = 0; p < 4; ++p) {
    int kk = (tid >> 4) + 16 * p, nq = tid & 15;
    f32x4 v = *(const f32x4*)(src + (size_t)(k0 + kk) * lds + n0 + 4 * nq);
#pragma unroll
    for (int j = 0; j < 4; ++j) tile[kk][4 * nq + j] = v[j];
  }
  __syncthreads();
#pragma unroll
  for (int p = 0; p < 2; ++p) {
    int nn = (tid >> 3) + 32 * p, kq = tid & 7;
    bf16x8 o;
#pragma unroll
    for (int i = 0; i < 8; ++i) o[i] = (short)f2bf(tile[8 * kq + i][nn]);
    *(bf16x8*)(dst + (size_t)(n0 + nn) * ldd + k0 + 8 * kq) = o;
  }
}

// ---------------- generic GEMM (precompute / epilogue) ----------------
// C(MxN) = A(MxK) @ B(KxN), A f32-or-bf16 row-major, B f32 row-major.
// TSTORE: write bf16 transposed out[n*ldo + m]  (for building Wcat halves)
// else : write f32 out[m*ldo + n]
template <bool ABF16, bool TSTORE>
__global__ void __launch_bounds__(256) gemm_k(const void* __restrict__ Aptr, int lda,
                                              const float* __restrict__ B, int ldb,
                                              void* __restrict__ outp, int ldo, int K) {
  const int m0 = blockIdx.x * 32;
  const int n0 = blockIdx.y * 64;
  __shared__ __align__(16) uint16_t As[32 * 40];
  __shared__ __align__(16) uint16_t Bs[64 * 40];
  __shared__ __align__(16) float Cs[32 * 64];
  const int tid = threadIdx.x;
  const int w = tid >> 6, lane = tid & 63;
  const int r16 = lane & 15, g = lane >> 4;

  f32x4 acc[2];
  acc[0] = (f32x4){0.f, 0.f, 0.f, 0.f};
  acc[1] = acc[0];

  for (int k0 = 0; k0 < K; k0 += 32) {
    {  // stage A tile 32x32 -> bf16
      int m = tid >> 3, kq = tid & 7;
      uint16_t* d = As + m * 40 + 4 * kq;
      if (ABF16) {
        const uint16_t* A = (const uint16_t*)Aptr;
        *(uint64_t*)d = *(const uint64_t*)(A + (size_t)(m0 + m) * lda + k0 + 4 * kq);
      } else {
        const float* A = (const float*)Aptr;
        f32x4 v = *(const f32x4*)(A + (size_t)(m0 + m) * lda + k0 + 4 * kq);
        uint64_t pk = (uint64_t)f2bf(v[0]) | ((uint64_t)f2bf(v[1]) << 16) |
                      ((uint64_t)f2bf(v[2]) << 32) | ((uint64_t)f2bf(v[3]) << 48);
        *(uint64_t*)d = pk;
      }
    }
#pragma unroll
    for (int p = 0; p < 2; ++p) {  // stage B tile 32k x 64n, transposed to [n][k]
      int k = (tid >> 4) + 16 * p, nq = tid & 15;
      f32x4 v = *(const f32x4*)(B + (size_t)(k0 + k) * ldb + n0 + 4 * nq);
#pragma unroll
      for (int j = 0; j < 4; ++j) Bs[(4 * nq + j) * 40 + k] = f2bf(v[j]);
    }
    __syncthreads();
    bf16x8 a0 = *(const bf16x8*)(As + r16 * 40 + 8 * g);
    bf16x8 a1 = *(const bf16x8*)(As + (r16 + 16) * 40 + 8 * g);
    bf16x8 b = *(const bf16x8*)(Bs + (16 * w + r16) * 40 + 8 * g);
    acc[0] = mfma16x16(a0, b, acc[0]);
    acc[1] = mfma16x16(a1, b, acc[1]);
    __syncthreads();
  }

  if (TSTORE) {
#pragma unroll
    for (int rt = 0; rt < 2; ++rt)
#pragma unroll
      for (int i2 = 0; i2 < 4; ++i2)
        Cs[(16 * rt + 4 * g + i2) * 64 + 16 * w + r16] = acc[rt][i2];
    __syncthreads();
    int nn = tid >> 2, mq = tid & 3;
    bf16x8 o;
#pragma unroll
    for (int i2 = 0; i2 < 8; ++i2) o[i2] = (short)f2bf(Cs[(8 * mq + i2) * 64 + nn]);
    uint16_t* dst = (uint16_t*)outp;
    *(bf16x8*)(dst + (size_t)(n0 + nn) * ldo + m0 + 8 * mq) = o;
  } else {
    float* C = (float*)outp;
#pragma unroll
    for (int rt = 0; rt < 2; ++rt)
#pragma unroll
      for (int i2 = 0; i2 < 4; ++i2)
        C[(size_t)(m0 + 16 * rt + 4 * g + i2) * ldo + n0 + 16 * w + r16] = acc[rt][i2];
  }
}

// ---------------- slot kernel (the serial section) ----------------
// grid 256 blocks x 256 thr. block = (layer l = blk>>6, h-slice slc = blk&63).
// Each block: 32 batch rows x 16 h-indices, all 4 gate strips.
// Waves split K (chunk c = 4*i + w). A staged in LDS (XOR-swizzled, 64KB),
// Wcat read straight from global (L2/L3 resident). Cross-wave reduce via LDS.

static __device__ __forceinline__ void mfma_phase(const uint8_t* sm, const uint16_t* Wl,
                                                  int kbase, int j0, int w, int r16, int g,
                                                  f32x4 acc[2][4]) {
#pragma unroll
  for (int i = 0; i < 8; ++i) {
    const int k0 = (4 * i + w) * 32;
    const uint32_t abyte = (uint32_t)((k0 + 8 * g) * 2);
    const uint32_t swz = (uint32_t)(r16 & 7) << 4;
    uint32_t o0 = (((uint32_t)r16) << 11) + abyte;
    o0 ^= swz;
    uint32_t o1 = (((uint32_t)(r16 + 16)) << 11) + abyte;
    o1 ^= swz;
    bf16x8 a0 = *(const bf16x8*)(sm + o0);
    bf16x8 a1 = *(const bf16x8*)(sm + o1);
#pragma unroll
    for (int s = 0; s < 4; ++s) {
      const uint16_t* bp = Wl + (size_t)(s * 1024 + j0 + r16) * KCAT + (kbase + k0 + 8 * g);
      bf16x8 b = *(const bf16x8*)bp;
      acc[0][s] = mfma16x16(a0, b, acc[0][s]);
      acc[1][s] = mfma16x16(a1, b, acc[1][s]);
    }
  }
}

__global__ void __launch_bounds__(256) lstm_slot(int slot, const float* __restrict__ x,
                                                 const float* __restrict__ wic,
                                                 const float* __restrict__ wfc,
                                                 const float* __restrict__ woc,
                                                 const float* __restrict__ r0,
                                                 const float* __restrict__ bias,
                                                 float* __restrict__ cstate,
                                                 const uint16_t* __restrict__ Wcat,
                                                 uint16_t* __restrict__ ring,
                                                 uint16_t* __restrict__ m3) {
  const int blk = blockIdx.x;
  const int l = blk >> 6;
  const int slc = blk & 63;
  const int t = slot - l;
  if (t < 0 || t >= TT) return;

  __shared__ __align__(16) uint8_t sm[65536];
  const int tid = threadIdx.x;
  const int w = tid >> 6, lane = tid & 63;
  const int r16 = lane & 15, g = lane >> 4;
  const int j0 = slc * 16;

  f32x4 acc[2][4];
#pragma unroll
  for (int a = 0; a < 2; ++a)
#pragma unroll
    for (int b = 0; b < 4; ++b) acc[a][b] = (f32x4){0.f, 0.f, 0.f, 0.f};

  // ---- phase 0: input half (x for layer0, m from layer below otherwise) ----
  if (l == 0) {
    const float* src = x + (size_t)t * (NBATCH * HID);
#pragma unroll
    for (int i = 0; i < 16; ++i) {
      int cid = i * 256 + tid;
      int r = cid >> 7, c = cid & 127;
      uint32_t off = ((uint32_t)r << 11) + ((uint32_t)c << 4);
      off ^= (uint32_t)(r & 7) << 4;
      const float* s0 = src + r * HID + c * 8;
      f32x4 v0 = *(const f32x4*)(s0);
      f32x4 v1 = *(const f32x4*)(s0 + 4);
      bf16x8 pk;
      pk[0] = (short)f2bf(v0[0]); pk[1] = (short)f2bf(v0[1]);
      pk[2] = (short)f2bf(v0[2]); pk[3] = (short)f2bf(v0[3]);
      pk[4] = (short)f2bf(v1[0]); pk[5] = (short)f2bf(v1[1]);
      pk[6] = (short)f2bf(v1[2]); pk[7] = (short)f2bf(v1[3]);
      *(bf16x8*)(sm + off) = pk;
    }
  } else {
    const uint16_t* src = ring + ((size_t)(l - 1) * 2 + (t & 1)) * (NBATCH * HID);
#pragma unroll
    for (int i = 0; i < 16; ++i) {
      int cid = i * 256 + tid;
      int r = cid >> 7, c = cid & 127;
      uint32_t off = ((uint32_t)r << 11) + ((uint32_t)c << 4);
      off ^= (uint32_t)(r & 7) << 4;
      *(f32x4*)(sm + off) = *(const f32x4*)(src + r * HID + c * 8);
    }
  }
  __syncthreads();
  const uint16_t* Wl = Wcat + (size_t)l * G4 * KCAT;
  mfma_phase(sm, Wl, 0, j0, w, r16, g, acc);
  __syncthreads();

  // ---- phase 1: own m_{t-1} (skip at t=0; r0 added in pointwise) ----
  if (t > 0) {
    const uint16_t* src = (l < 3) ? ring + ((size_t)l * 2 + ((t - 1) & 1)) * (NBATCH * HID)
                                  : m3 + (size_t)(t - 1) * (NBATCH * HID);
#pragma unroll
    for (int i = 0; i < 16; ++i) {
      int cid = i * 256 + tid;
      int r = cid >> 7, c = cid & 127;
      uint32_t off = ((uint32_t)r << 11) + ((uint32_t)c << 4);
      off ^= (uint32_t)(r & 7) << 4;
      *(f32x4*)(sm + off) = *(const f32x4*)(src + r * HID + c * 8);
    }
    __syncthreads();
    mfma_phase(sm, Wl, 1024, j0, w, r16, g, acc);
    __syncthreads();
  }

  // ---- cross-wave reduce ----
  float* red = (float*)sm;  // 4 waves x 8 tiles x 64 lanes x 4 f32 = 32KB
#pragma unroll
  for (int rt = 0; rt < 2; ++rt)
#pragma unroll
    for (int s = 0; s < 4; ++s)
      *(f32x4*)(red + (size_t)(((w * 8 + rt * 4 + s) * 64 + lane) * 4)) = acc[rt][s];
  __syncthreads();

  // ---- gate pointwise: 2 elems per thread (32 rows x 16 h-idx) ----
  {
    int e = tid * 2;
    int r = e >> 4;
    int jj = e & 15;
    int rt = r >> 4, reg = r & 3;
    int lanebase = ((r & 15) >> 2) * 16;
    float gate[2][4];
#pragma unroll
    for (int q = 0; q < 2; ++q) {
      int lanec = lanebase + jj + q;
#pragma unroll
      for (int s = 0; s < 4; ++s) {
        float v = 0.f;
#pragma unroll
        for (int w2 = 0; w2 < 4; ++w2) v += red[((w2 * 8 + rt * 4 + s) * 64 + lanec) * 4 + reg];
        gate[q][s] = v;
      }
    }
    const float* wicl = wic + l * HID;
    const float* wfcl = wfc + l * HID;
    const float* wocl = woc + l * HID;
    const float* bl = bias + l * G4;
    const float* r0l = r0 + ((size_t)l * NBATCH + r) * G4;
    float* cl = cstate + ((size_t)l * NBATCH + r) * HID;
    uint16_t* mout = ((l < 3) ? ring + ((size_t)l * 2 + (t & 1)) * (NBATCH * HID)
                              : m3 + (size_t)t * (NBATCH * HID)) +
                     r * HID;
    uint32_t packed = 0;
#pragma unroll
    for (int q = 0; q < 2; ++q) {
      int hj = j0 + jj + q;
      float ai = gate[q][0] + bl[hj];
      float af = gate[q][1] + bl[1024 + hj];
      float ag = gate[q][2] + bl[2048 + hj];
      float ao = gate[q][3] + bl[3072 + hj];
      if (t == 0) {
        ai += r0l[hj];
        af += r0l[1024 + hj];
        ag += r0l[2048 + hj];
        ao += r0l[3072 + hj];
      }
      float cold = cl[hj];
      float iv = sigm(ai + cold * wicl[hj]);
      float fv = sigm(af + cold * wfcl[hj]);
      float gv = tanh_(ag);
      float nc = fv * cold + iv * gv;
      float ov = sigm(ao + nc * wocl[hj]);
      float mv = ov * tanh_(nc);
      cl[hj] = nc;
      packed |= ((uint32_t)f2bf(mv)) << (16 * q);
    }
    *(uint32_t*)(mout + j0 + jj) = packed;
  }
}

// ---------------- host ----------------
extern "C" void kernel_launch(void* const* d_in, const int* in_sizes, int n_in, void* d_out,
                              int out_size, void* d_ws, size_t ws_size, hipStream_t stream) {
  (void)in_sizes; (void)n_in; (void)out_size; (void)ws_size;
  const float* x = (const float*)d_in[0];
  const float* h0 = (const float*)d_in[1];
  const float* c0 = (const float*)d_in[2];
  const float* wih = (const float*)d_in[3];
  const float* whh = (const float*)d_in[4];
  const float* bih = (const float*)d_in[5];
  const float* bhh = (const float*)d_in[6];
  const float* wic = (const float*)d_in[7];
  const float* wfc = (const float*)d_in[8];
  const float* woc = (const float*)d_in[9];
  const float* whm = (const float*)d_in[10];

  float* ys = (float*)d_out;
  float* hs = ys + (size_t)TT * NBATCH * HID;
  float* cs = hs + (size_t)4 * NBATCH * HID;

  uint8_t* ws = (uint8_t*)d_ws;
  uint16_t* Wcat = (uint16_t*)(ws);
  uint16_t* m3 = (uint16_t*)(ws + 67108864);
  uint16_t* ring = (uint16_t*)(ws + 67108864 + 33554432);
  float* r0 = (float*)(ws + 67108864 + 33554432 + 393216);
  float* bias = (float*)(ws + 67108864 + 33554432 + 393216 + 2097152);

  // c state lives directly in d_out's cs section; init from c0
  hipMemcpyAsync(cs, c0, (size_t)4 * NBATCH * HID * sizeof(float), hipMemcpyDeviceToDevice,
                 stream);
  add_bias<<<64, 256, 0, stream>>>(bih, bhh, bias, 4 * G4);
  // Wcat layer0 first half = wih0^T
  transpose_cast<<<dim3(16, 64), 256, 0, stream>>>(wih, G4, Wcat, KCAT);
  // W1^l = whm^{l-1} @ wih^l  (l=1..3), transposed-bf16 into Wcat first half
  for (int l = 1; l < 4; ++l)
    gemm_k<false, true><<<dim3(32, 64), 256, 0, stream>>>(
        whm + (size_t)(l - 1) * 1048576, 1024, wih + (size_t)l * 4194304, G4,
        Wcat + (size_t)l * 8388608, KCAT, 1024);
  // W2^l = whm^l @ whh^l, into Wcat second half (k offset 1024)
  for (int l = 0; l < 4; ++l)
    gemm_k<false, true><<<dim3(32, 64), 256, 0, stream>>>(
        whm + (size_t)l * 1048576, 1024, whh + (size_t)l * 4194304, G4,
        Wcat + (size_t)l * 8388608 + 1024, KCAT, 1024);
  // r0^l = h0^l @ whh^l  (f32)
  for (int l = 0; l < 4; ++l)
    gemm_k<false, false><<<dim3(1, 64), 256, 0, stream>>>(
        h0 + (size_t)l * 32768, 1024, whh + (size_t)l * 4194304, G4, r0 + (size_t)l * 131072,
        G4, 1024);

  // the recurrence: 515 diagonal slots
  for (int s = 0; s < TT + 3; ++s)
    lstm_slot<<<256, 256, 0, stream>>>(s, x, wic, wfc, woc, r0, bias, cs, Wcat, ring, m3);

  // hT^l = m^l_{T-1} @ whm^l
  for (int l = 0; l < 4; ++l) {
    const uint16_t* mlast =
        (l < 3) ? ring + ((size_t)l * 2 + 1) * (NBATCH * HID) : m3 + (size_t)(TT - 1) * (NBATCH * HID);
    gemm_k<true, false><<<dim3(1, 16), 256, 0, stream>>>(mlast, 1024,
                                                         whm + (size_t)l * 1048576, 1024,
                                                         hs + (size_t)l * 32768, 1024, 1024);
  }
  // ys = M3 @ whm^3
  gemm_k<true, false><<<dim3(512, 16), 256, 0, stream>>>(m3, 1024, whm + (size_t)3 * 1048576,
                                                         1024, ys, 1024, 1024);
}

// Round 2
// 8592.506 us; speedup vs baseline: 1.2428x; 1.2428x over previous
//
#include <hip/hip_runtime.h>
#include <hip/hip_bf16.h>
#include <cstdint>
#include <cstddef>

// LSTM w/ projection + peepholes, MI355X gfx950.
// T=512 N=32 D=H=P=1024 L=4.
// m = o*tanh(c) passed between layers/steps; projection folded into weights:
//   W1^l = whm^{l-1} @ wih^l (l>=1; layer0 uses wih0), W2^l = whm^l @ whh^l
// Slot kernel (serial path): a = bias + [in; m_prev](32x2048) @ Wcat^T.
// Diagonal pipeline: slot s runs layer l at t = s - l (515 slot kernels).
//
// Workspace layout (bytes), total ~146.4 MB:
//   0           Wcat    67,108,864  bf16 [l][4096][2048]
//   67,108,864  m3      33,554,432  bf16 (ALIAS during precompute: wihT l=1..3)
//   100,663,296 xbf     33,554,432  bf16 (ALIAS during precompute: whhT l=0..3)
//   134,217,728 whm_bf   8,388,608
//   142,606,336 whmT_bf  8,388,608
//   150,994,944 ring       393,216
//   151,388,160 r0       2,097,152
//   153,485,312 bias        65,536

#define TT 512
#define NBATCH 32
#define HID 1024
#define G4 4096
#define KCAT 2048

typedef __attribute__((ext_vector_type(4))) float f32x4;
typedef __attribute__((ext_vector_type(8))) short bf16x8;

static __device__ __forceinline__ uint16_t f2bf(float f) {
  uint32_t u = __builtin_bit_cast(uint32_t, f);
  uint32_t lsb = (u >> 16) & 1u;
  u += 0x7fffu + lsb;  // RNE
  return (uint16_t)(u >> 16);
}

static __device__ __forceinline__ f32x4 mfma16x16(bf16x8 a, bf16x8 b, f32x4 c) {
  return __builtin_amdgcn_mfma_f32_16x16x32_bf16(a, b, c, 0, 0, 0);
}

static __device__ __forceinline__ float sigm(float v) { return 1.f / (1.f + __expf(-v)); }
static __device__ __forceinline__ float tanh_(float v) {
  float a = fabsf(v);
  float e = __expf(-2.f * a);
  float t = (1.f - e) / (1.f + e);
  return v < 0.f ? -t : t;
}

// ---------------- small helpers ----------------
__global__ void __launch_bounds__(256) add_bias(const float* __restrict__ a,
                                                const float* __restrict__ b,
                                                float* __restrict__ o, int n) {
  int i = blockIdx.x * 256 + threadIdx.x;
  if (i < n) o[i] = a[i] + b[i];
}

__global__ void __launch_bounds__(256) cast_bf16(const float* __restrict__ src,
                                                 uint16_t* __restrict__ dst, int n8) {
  int i = blockIdx.x * 256 + threadIdx.x;
  if (i >= n8) return;
  const float* s = src + (size_t)i * 8;
  f32x4 v0 = *(const f32x4*)s;
  f32x4 v1 = *(const f32x4*)(s + 4);
  bf16x8 o;
  o[0] = (short)f2bf(v0[0]); o[1] = (short)f2bf(v0[1]);
  o[2] = (short)f2bf(v0[2]); o[3] = (short)f2bf(v0[3]);
  o[4] = (short)f2bf(v1[0]); o[5] = (short)f2bf(v1[1]);
  o[6] = (short)f2bf(v1[2]); o[7] = (short)f2bf(v1[3]);
  *(bf16x8*)(dst + (size_t)i * 8) = o;
}

// src f32 (K x N) row-major -> dst bf16 [n][k] (ld ldd), 64x64 tiles
__global__ void __launch_bounds__(256) transpose_cast(const float* __restrict__ src, int lds,
                                                      uint16_t* __restrict__ dst, int ldd) {
  const int k0 = blockIdx.x * 64;
  const int n0 = blockIdx.y * 64;
  __shared__ float tile[64][65];
  const int tid = threadIdx.x;
#pragma unroll
  for (int p = 0; p < 4; ++p) {
    int kk = (tid >> 4) + 16 * p, nq = tid & 15;
    f32x4 v = *(const f32x4*)(src + (size_t)(k0 + kk) * lds + n0 + 4 * nq);
#pragma unroll
    for (int j = 0; j < 4; ++j) tile[kk][4 * nq + j] = v[j];
  }
  __syncthreads();
#pragma unroll
  for (int p = 0; p < 2; ++p) {
    int nn = (tid >> 3) + 32 * p, kq = tid & 7;
    bf16x8 o;
#pragma unroll
    for (int i = 0; i < 8; ++i) o[i] = (short)f2bf(tile[8 * kq + i][nn]);
    *(bf16x8*)(dst + (size_t)(n0 + nn) * ldd + k0 + 8 * kq) = o;
  }
}

// ---------------- tiled GEMM: C[M][N] = A[M][K]bf16 @ Bt[N][K]bf16^T ----------------
// 128x128 tile, BK=32, 4 waves (64x64 each, 4x4 frags). M may be partial.
template <bool OBF16>
__global__ void __launch_bounds__(256) gemm_tn(const uint16_t* __restrict__ A, int lda, int M,
                                               const uint16_t* __restrict__ Bt, int ldb,
                                               void* __restrict__ Cp, int ldc, int K) {
  const int m0 = blockIdx.x * 128, n0 = blockIdx.y * 128;
  __shared__ __align__(16) uint16_t As[128 * 40];
  __shared__ __align__(16) uint16_t Bs[128 * 40];
  const int tid = threadIdx.x;
  const int w = tid >> 6, lane = tid & 63, r16 = lane & 15, g = lane >> 4;
  f32x4 acc[4][4];
#pragma unroll
  for (int a = 0; a < 4; ++a)
#pragma unroll
    for (int b = 0; b < 4; ++b) acc[a][b] = (f32x4){0.f, 0.f, 0.f, 0.f};

  for (int k0 = 0; k0 < K; k0 += 32) {
#pragma unroll
    for (int q = 0; q < 2; ++q) {
      int c = q * 256 + tid, row = c >> 2, col = (c & 3) * 8;
      bf16x8 va = (bf16x8){0, 0, 0, 0, 0, 0, 0, 0};
      if (m0 + row < M) va = *(const bf16x8*)(A + (size_t)(m0 + row) * lda + k0 + col);
      *(bf16x8*)(As + row * 40 + col) = va;
      bf16x8 vb = *(const bf16x8*)(Bt + (size_t)(n0 + row) * ldb + k0 + col);
      *(bf16x8*)(Bs + row * 40 + col) = vb;
    }
    __syncthreads();
    bf16x8 bfr[4];
#pragma unroll
    for (int nf = 0; nf < 4; ++nf)
      bfr[nf] = *(const bf16x8*)(Bs + ((w >> 1) * 64 + nf * 16 + r16) * 40 + 8 * g);
#pragma unroll
    for (int mf = 0; mf < 4; ++mf) {
      bf16x8 a = *(const bf16x8*)(As + ((w & 1) * 64 + mf * 16 + r16) * 40 + 8 * g);
#pragma unroll
      for (int nf = 0; nf < 4; ++nf) acc[mf][nf] = mfma16x16(a, bfr[nf], acc[mf][nf]);
    }
    __syncthreads();
  }
#pragma unroll
  for (int mf = 0; mf < 4; ++mf)
#pragma unroll
    for (int nf = 0; nf < 4; ++nf)
#pragma unroll
      for (int reg = 0; reg < 4; ++reg) {
        int row = m0 + (w & 1) * 64 + mf * 16 + (lane >> 4) * 4 + reg;
        int col = n0 + (w >> 1) * 64 + nf * 16 + (lane & 15);
        if (row < M) {
          if (OBF16)
            ((uint16_t*)Cp)[(size_t)row * ldc + col] = f2bf(acc[mf][nf][reg]);
          else
            ((float*)Cp)[(size_t)row * ldc + col] = acc[mf][nf][reg];
        }
      }
}

// ---------------- f32 GEMM for r0 = h0 @ whh (M=32) ----------------
__global__ void __launch_bounds__(256) gemm32_f32(const float* __restrict__ A, int lda,
                                                  const float* __restrict__ B, int ldb,
                                                  float* __restrict__ C, int ldc, int K) {
  const int n0 = blockIdx.x * 64;
  __shared__ __align__(16) uint16_t As[32 * 40];
  __shared__ __align__(16) uint16_t Bs[64 * 40];
  const int tid = threadIdx.x;
  const int w = tid >> 6, lane = tid & 63, r16 = lane & 15, g = lane >> 4;
  f32x4 acc[2];
  acc[0] = (f32x4){0.f, 0.f, 0.f, 0.f};
  acc[1] = acc[0];
  for (int k0 = 0; k0 < K; k0 += 32) {
    {
      int m = tid >> 3, kq = tid & 7;
      f32x4 v = *(const f32x4*)(A + (size_t)m * lda + k0 + 4 * kq);
      uint64_t pk = (uint64_t)f2bf(v[0]) | ((uint64_t)f2bf(v[1]) << 16) |
                    ((uint64_t)f2bf(v[2]) << 32) | ((uint64_t)f2bf(v[3]) << 48);
      *(uint64_t*)(As + m * 40 + 4 * kq) = pk;
    }
#pragma unroll
    for (int p = 0; p < 2; ++p) {
      int k = (tid >> 4) + 16 * p, nq = tid & 15;
      f32x4 v = *(const f32x4*)(B + (size_t)(k0 + k) * ldb + n0 + 4 * nq);
#pragma unroll
      for (int j = 0; j < 4; ++j) Bs[(4 * nq + j) * 40 + k] = f2bf(v[j]);
    }
    __syncthreads();
    bf16x8 a0 = *(const bf16x8*)(As + r16 * 40 + 8 * g);
    bf16x8 a1 = *(const bf16x8*)(As + (r16 + 16) * 40 + 8 * g);
    bf16x8 b = *(const bf16x8*)(Bs + (16 * w + r16) * 40 + 8 * g);
    acc[0] = mfma16x16(a0, b, acc[0]);
    acc[1] = mfma16x16(a1, b, acc[1]);
    __syncthreads();
  }
#pragma unroll
  for (int rt = 0; rt < 2; ++rt)
#pragma unroll
    for (int reg = 0; reg < 4; ++reg)
      C[(size_t)(16 * rt + 4 * g + reg) * ldc + n0 + 16 * w + r16] = acc[rt][reg];
}

// ---------------- slot kernel ----------------
// 256 blocks x 512 thr (8 waves). block = (layer l=blk>>6, h-slice slc=blk&63).
// Block: 32 batch rows x 16 h x 4 gates, K=2048 split 8 ways across waves.
// A fragments read DIRECTLY from global bf16 (L2-hot); B (Wcat) streamed from
// L2/L3. Single barrier, LDS only for the cross-wave reduce.
__global__ void __launch_bounds__(512) lstm_slot(int slot, const uint16_t* __restrict__ xbf,
                                                 const float* __restrict__ wic,
                                                 const float* __restrict__ wfc,
                                                 const float* __restrict__ woc,
                                                 const float* __restrict__ r0,
                                                 const float* __restrict__ bias,
                                                 float* __restrict__ cstate,
                                                 const uint16_t* __restrict__ Wcat,
                                                 uint16_t* __restrict__ ring,
                                                 uint16_t* __restrict__ m3) {
  const int blk = blockIdx.x;
  const int l = blk >> 6;
  const int slc = blk & 63;
  const int t = slot - l;
  if (t < 0 || t >= TT) return;

  __shared__ __align__(16) float red[16384];  // 64 KB
  const int tid = threadIdx.x;
  const int w = tid >> 6, lane = tid & 63;
  const int r16 = lane & 15, g = lane >> 4;
  const int j0 = slc * 16;
  const uint16_t* Wl = Wcat + (size_t)l * G4 * KCAT;

  f32x4 acc[2][4];
#pragma unroll
  for (int a = 0; a < 2; ++a)
#pragma unroll
    for (int b = 0; b < 4; ++b) acc[a][b] = (f32x4){0.f, 0.f, 0.f, 0.f};

  // phase 0: input half (xbf for layer0, m from layer below otherwise)
  {
    const uint16_t* s0 = (l == 0) ? xbf + (size_t)t * (NBATCH * HID)
                                  : ring + ((size_t)(l - 1) * 2 + (t & 1)) * (NBATCH * HID);
#pragma unroll
    for (int i = 0; i < 4; ++i) {
      const int k0 = (i * 8 + w) * 32;
      bf16x8 a0 = *(const bf16x8*)(s0 + r16 * HID + k0 + 8 * g);
      bf16x8 a1 = *(const bf16x8*)(s0 + (r16 + 16) * HID + k0 + 8 * g);
#pragma unroll
      for (int s = 0; s < 4; ++s) {
        bf16x8 b = *(const bf16x8*)(Wl + (size_t)(s * 1024 + j0 + r16) * KCAT + k0 + 8 * g);
        acc[0][s] = mfma16x16(a0, b, acc[0][s]);
        acc[1][s] = mfma16x16(a1, b, acc[1][s]);
      }
    }
  }
  // phase 1: own m_{t-1} (skip at t=0; r0 added in pointwise)
  if (t > 0) {
    const uint16_t* s1 = (l < 3) ? ring + ((size_t)l * 2 + ((t - 1) & 1)) * (NBATCH * HID)
                                 : m3 + (size_t)(t - 1) * (NBATCH * HID);
#pragma unroll
    for (int i = 0; i < 4; ++i) {
      const int k0 = (i * 8 + w) * 32;
      bf16x8 a0 = *(const bf16x8*)(s1 + r16 * HID + k0 + 8 * g);
      bf16x8 a1 = *(const bf16x8*)(s1 + (r16 + 16) * HID + k0 + 8 * g);
#pragma unroll
      for (int s = 0; s < 4; ++s) {
        bf16x8 b =
            *(const bf16x8*)(Wl + (size_t)(s * 1024 + j0 + r16) * KCAT + 1024 + k0 + 8 * g);
        acc[0][s] = mfma16x16(a0, b, acc[0][s]);
        acc[1][s] = mfma16x16(a1, b, acc[1][s]);
      }
    }
  }

  // cross-wave reduce: wave w writes its partials
#pragma unroll
  for (int rt = 0; rt < 2; ++rt)
#pragma unroll
    for (int s = 0; s < 4; ++s)
      *(f32x4*)(red + (size_t)((w * 8 + rt * 4 + s) * 64 + lane) * 4) = acc[rt][s];
  __syncthreads();

  // pointwise: 1 elem/thread (r = batch row, jj = h within slice)
  {
    const int r = tid >> 4, jj = tid & 15;
    const int rt = r >> 4, reg = r & 3;
    const int lanec = ((r & 15) >> 2) * 16 + jj;
    float gate[4];
#pragma unroll
    for (int s = 0; s < 4; ++s) {
      float v = 0.f;
#pragma unroll
      for (int w2 = 0; w2 < 8; ++w2)
        v += red[(size_t)((w2 * 8 + rt * 4 + s) * 64 + lanec) * 4 + reg];
      gate[s] = v;
    }
    const int hj = j0 + jj;
    const float* bl = bias + l * G4;
    float ai = gate[0] + bl[hj];
    float af = gate[1] + bl[1024 + hj];
    float ag = gate[2] + bl[2048 + hj];
    float ao = gate[3] + bl[3072 + hj];
    if (t == 0) {
      const float* r0l = r0 + ((size_t)l * NBATCH + r) * G4;
      ai += r0l[hj];
      af += r0l[1024 + hj];
      ag += r0l[2048 + hj];
      ao += r0l[3072 + hj];
    }
    float* cl = cstate + ((size_t)l * NBATCH + r) * HID;
    float cold = cl[hj];
    float iv = sigm(ai + cold * wic[l * HID + hj]);
    float fv = sigm(af + cold * wfc[l * HID + hj]);
    float gv = tanh_(ag);
    float nc = fv * cold + iv * gv;
    float ov = sigm(ao + nc * woc[l * HID + hj]);
    float mv = ov * tanh_(nc);
    cl[hj] = nc;
    uint16_t* mout = ((l < 3) ? ring + ((size_t)l * 2 + (t & 1)) * (NBATCH * HID)
                              : m3 + (size_t)t * (NBATCH * HID)) +
                     (size_t)r * HID;
    mout[hj] = f2bf(mv);
  }
}

// ---------------- host ----------------
extern "C" void kernel_launch(void* const* d_in, const int* in_sizes, int n_in, void* d_out,
                              int out_size, void* d_ws, size_t ws_size, hipStream_t stream) {
  (void)in_sizes; (void)n_in; (void)out_size; (void)ws_size;
  const float* x = (const float*)d_in[0];
  const float* h0 = (const float*)d_in[1];
  const float* c0 = (const float*)d_in[2];
  const float* wih = (const float*)d_in[3];
  const float* whh = (const float*)d_in[4];
  const float* bih = (const float*)d_in[5];
  const float* bhh = (const float*)d_in[6];
  const float* wic = (const float*)d_in[7];
  const float* wfc = (const float*)d_in[8];
  const float* woc = (const float*)d_in[9];
  const float* whm = (const float*)d_in[10];

  float* ys = (float*)d_out;
  float* hs = ys + (size_t)TT * NBATCH * HID;
  float* cs = hs + (size_t)4 * NBATCH * HID;

  uint8_t* ws = (uint8_t*)d_ws;
  uint16_t* Wcat = (uint16_t*)(ws);
  uint16_t* m3 = (uint16_t*)(ws + 67108864ull);
  uint16_t* wihT = m3;  // alias (precompute only), layers 1..3 at (l-1)*4194304
  uint16_t* xbf = (uint16_t*)(ws + 100663296ull);
  uint16_t* whhT = xbf;  // alias (precompute only), layers 0..3 at l*4194304
  uint16_t* whm_bf = (uint16_t*)(ws + 134217728ull);
  uint16_t* whmT = (uint16_t*)(ws + 142606336ull);
  uint16_t* ring = (uint16_t*)(ws + 150994944ull);
  float* r0 = (float*)(ws + 151388160ull);
  float* bias = (float*)(ws + 153485312ull);

  hipMemcpyAsync(cs, c0, (size_t)4 * NBATCH * HID * sizeof(float), hipMemcpyDeviceToDevice,
                 stream);
  add_bias<<<64, 256, 0, stream>>>(bih, bhh, bias, 4 * G4);
  // bf16 casts / transposes of weights
  cast_bf16<<<2048, 256, 0, stream>>>(whm, whm_bf, 524288);
  for (int l = 0; l < 4; ++l)
    transpose_cast<<<dim3(16, 16), 256, 0, stream>>>(whm + (size_t)l * 1048576, 1024,
                                                     whmT + (size_t)l * 1048576, 1024);
  // Wcat[0] first half = wih0^T (direct)
  transpose_cast<<<dim3(16, 64), 256, 0, stream>>>(wih, G4, Wcat, KCAT);
  for (int l = 1; l < 4; ++l)
    transpose_cast<<<dim3(16, 64), 256, 0, stream>>>(wih + (size_t)l * 4194304, G4,
                                                     wihT + (size_t)(l - 1) * 4194304, 1024);
  for (int l = 0; l < 4; ++l)
    transpose_cast<<<dim3(16, 64), 256, 0, stream>>>(whh + (size_t)l * 4194304, G4,
                                                     whhT + (size_t)l * 4194304, 1024);
  // W1^l,T = wihT[l] @ whm_bf[l-1]^T-supplied  -> Wcat first half (bf16)
  for (int l = 1; l < 4; ++l)
    gemm_tn<true><<<dim3(32, 8), 256, 0, stream>>>(
        wihT + (size_t)(l - 1) * 4194304, 1024, 4096, whm_bf + (size_t)(l - 1) * 1048576, 1024,
        Wcat + (size_t)l * 8388608, KCAT, 1024);
  // W2^l,T = whhT[l] @ whm_bf[l] -> Wcat second half
  for (int l = 0; l < 4; ++l)
    gemm_tn<true><<<dim3(32, 8), 256, 0, stream>>>(
        whhT + (size_t)l * 4194304, 1024, 4096, whm_bf + (size_t)l * 1048576, 1024,
        Wcat + (size_t)l * 8388608 + 1024, KCAT, 1024);
  // r0^l = h0^l @ whh^l (f32)
  for (int l = 0; l < 4; ++l)
    gemm32_f32<<<64, 256, 0, stream>>>(h0 + (size_t)l * 32768, 1024,
                                       whh + (size_t)l * 4194304, G4, r0 + (size_t)l * 131072,
                                       G4, 1024);
  // x -> bf16 (AFTER gemms: xbf aliases whhT)
  cast_bf16<<<8192, 256, 0, stream>>>(x, xbf, 2097152);

  // the recurrence: 515 diagonal slots
  for (int s = 0; s < TT + 3; ++s)
    lstm_slot<<<256, 512, 0, stream>>>(s, xbf, wic, wfc, woc, r0, bias, cs, Wcat, ring, m3);

  // ys = M3 @ whm3  (Bt = whmT[3])
  gemm_tn<false><<<dim3(128, 8), 256, 0, stream>>>(m3, 1024, 16384,
                                                   whmT + (size_t)3 * 1048576, 1024, ys, 1024,
                                                   1024);
  // hT^l = m_last^l @ whm^l
  for (int l = 0; l < 4; ++l) {
    const uint16_t* mlast = (l < 3) ? ring + ((size_t)l * 2 + 1) * (NBATCH * HID)
                                    : m3 + (size_t)(TT - 1) * (NBATCH * HID);
    gemm_tn<false><<<dim3(1, 8), 256, 0, stream>>>(mlast, 1024, 32,
                                                   whmT + (size_t)l * 1048576, 1024,
                                                   hs + (size_t)l * 32768, 1024, 1024);
  }
}